// Round 4
// baseline (397.720 us; speedup 1.0000x reference)
//
#include <hip/hip_runtime.h>
#include <math.h>

#define N_NODES 50000
#define N_EDGES 800000
#define HEADS 4
#define N_GRAPHS 64
#define NEG_SLOPE 0.2f
#define LOG2E 1.4426950408889634f
#define SCAN_NB 196            // 196*256 = 50176 >= N_NODES
#define POOL_CHUNK 200
#define POOL_NB 250            // 250*200 = 50000 exactly
#define FEAT_NB 782            // ceil(50000/64)
#define EDGE_Q 200000          // N_EDGES/4: 4 edges per thread
#define EDGE_NB 782            // ceil(200000/256)

typedef __attribute__((ext_vector_type(8))) short bf16x8;
typedef __attribute__((ext_vector_type(4))) float f32x4;

// monotone float<->uint key for atomicMax-based segment max (pooling).
__device__ __forceinline__ unsigned fkey(float f) {
    unsigned u = __float_as_uint(f);
    return (u & 0x80000000u) ? ~u : (u | 0x80000000u);
}
__device__ __forceinline__ float kval(unsigned k) {
    unsigned u = (k & 0x80000000u) ? (k & 0x7FFFFFFFu) : ~k;
    return __uint_as_float(u);
}

// f32 -> bf16 (RNE), two packed into one uint (lo = first channel)
__device__ __forceinline__ unsigned short f2bf(float f) {
    unsigned u = __float_as_uint(f);
    u += 0x7FFFu + ((u >> 16) & 1u);
    return (unsigned short)(u >> 16);
}
__device__ __forceinline__ unsigned pack_bf2(float a, float b) {
    return (unsigned)f2bf(a) | ((unsigned)f2bf(b) << 16);
}

// ---------------- CSR build (counting sort by dst, rank-based) ----------------

__global__ void hist_kernel(const int* __restrict__ dst, int* __restrict__ deg,
                            int* __restrict__ rank) {
    int i = blockIdx.x * 256 + threadIdx.x;
    if (i >= EDGE_Q) return;
    int e0 = i, e1 = i + EDGE_Q, e2 = i + 2 * EDGE_Q, e3 = i + 3 * EDGE_Q;
    int d0 = dst[e0], d1 = dst[e1], d2 = dst[e2], d3 = dst[e3];
    int r0 = atomicAdd(&deg[d0], 1);
    int r1 = atomicAdd(&deg[d1], 1);
    int r2 = atomicAdd(&deg[d2], 1);
    int r3 = atomicAdd(&deg[d3], 1);
    rank[e0] = r0; rank[e1] = r1; rank[e2] = r2; rank[e3] = r3;
}

__global__ void partial_kernel(const int* __restrict__ deg, int* __restrict__ partial) {
    int t = threadIdx.x, b = blockIdx.x;
    int i = b * 256 + t;
    int v = (i < N_NODES) ? deg[i] : 0;
    #pragma unroll
    for (int off = 1; off < 64; off <<= 1) v += __shfl_xor(v, off, 64);
    __shared__ int wsum[4];
    if ((t & 63) == 0) wsum[t >> 6] = v;
    __syncthreads();
    if (t == 0) partial[b] = wsum[0] + wsum[1] + wsum[2] + wsum[3];
}

__global__ void csr_offsets_kernel(const int* __restrict__ deg, const int* __restrict__ partial,
                                   int* __restrict__ row_start) {
    __shared__ int sb[SCAN_NB];
    __shared__ int wsumA[4];
    __shared__ int wsumB[4];
    int t = threadIdx.x, b = blockIdx.x;
    int lane = t & 63, w = t >> 6;
    {   // exclusive scan of partial -> sb
        int v = (t < SCAN_NB) ? partial[t] : 0;
        int incl = v;
        #pragma unroll
        for (int off = 1; off < 64; off <<= 1) {
            int u = __shfl_up(incl, off, 64);
            if (lane >= off) incl += u;
        }
        if (lane == 63) wsumA[w] = incl;
        __syncthreads();
        int woff = 0;
        #pragma unroll
        for (int k = 0; k < 4; ++k) if (k < w) woff += wsumA[k];
        if (t < SCAN_NB) sb[t] = woff + incl - v;
        __syncthreads();
    }
    int i = b * 256 + t;
    int v = (i < N_NODES) ? deg[i] : 0;
    int incl = v;
    #pragma unroll
    for (int off = 1; off < 64; off <<= 1) {
        int u = __shfl_up(incl, off, 64);
        if (lane >= off) incl += u;
    }
    if (lane == 63) wsumB[w] = incl;
    __syncthreads();
    int woff = sb[b];
    #pragma unroll
    for (int k = 0; k < 4; ++k) if (k < w) woff += wsumB[k];
    int excl = woff + incl - v;
    if (i < N_NODES) row_start[i] = excl;
    else if (i == N_NODES) row_start[i] = excl;   // == N_EDGES
}

__device__ __forceinline__ void scatter_body(int bid, const int* __restrict__ src,
                                             const int* __restrict__ dst,
                                             const int* __restrict__ rank,
                                             const int* __restrict__ row_start,
                                             int* __restrict__ csr_src) {
    int i = bid * 256 + threadIdx.x;
    if (i >= EDGE_Q) return;
    int e0 = i, e1 = i + EDGE_Q, e2 = i + 2 * EDGE_Q, e3 = i + 3 * EDGE_Q;
    int d0 = dst[e0], d1 = dst[e1], d2 = dst[e2], d3 = dst[e3];
    int k0 = rank[e0], k1 = rank[e1], k2 = rank[e2], k3 = rank[e3];
    int s0 = src[e0], s1 = src[e1], s2 = src[e2], s3 = src[e3];
    csr_src[row_start[d0] + k0] = s0;
    csr_src[row_start[d1] + k1] = s1;
    csr_src[row_start[d2] + k2] = s2;
    csr_src[row_start[d3] + k3] = s3;
}

// ---------------- node pipeline ----------------

// Pre-pack W into MFMA B-fragment lane order (bf16).
__device__ __forceinline__ void wfrag_body(const float* __restrict__ W,
                                           unsigned* __restrict__ wf, int slot) {
    int f = slot >> 6, l = slot & 63;
    int n = l & 15, q = l >> 4;
    int ct = f >> 2, kq = f & 3;
    int col = 16 * ct + n;
    int k0 = 32 * kq + 8 * q;
    uint4 o;
    o.x = pack_bf2(W[(k0 + 0) * 128 + col], W[(k0 + 1) * 128 + col]);
    o.y = pack_bf2(W[(k0 + 2) * 128 + col], W[(k0 + 3) * 128 + col]);
    o.z = pack_bf2(W[(k0 + 4) * 128 + col], W[(k0 + 5) * 128 + col]);
    o.w = pack_bf2(W[(k0 + 6) * 128 + col], W[(k0 + 7) * 128 + col]);
    ((uint4*)wf)[slot] = o;
}

// prep: W-frag packs + zero deg + zero deg2 (probe scratch) + zero pkeys.
__global__ void prep_kernel(const float* __restrict__ W0, const float* __restrict__ W1,
                            unsigned* __restrict__ wf0, unsigned* __restrict__ wf1,
                            int* __restrict__ deg, int* __restrict__ deg2,
                            unsigned* __restrict__ pkeys) {
    int b = blockIdx.x, t = threadIdx.x;
    if (b < 8) {
        wfrag_body(W0, wf0, b * 256 + t);
    } else if (b < 16) {
        wfrag_body(W1, wf1, (b - 8) * 256 + t);
    } else if (b < 16 + SCAN_NB) {
        int i = (b - 16) * 256 + t;
        if (i < N_NODES) deg[i] = 0;
    } else if (b < 16 + 2 * SCAN_NB) {
        int i = (b - 16 - SCAN_NB) * 256 + t;
        if (i < N_NODES) deg2[i] = 0;
    } else {
        int i = (b - 16 - 2 * SCAN_NB) * 256 + t;
        if (i < N_GRAPHS * 128) pkeys[i] = 0;
    }
}

// feat = h @ W via MFMA 16x16x32 bf16.
template<int IN_BF16>
__device__ __forceinline__ void feat_body(int bid, const void* __restrict__ hin,
                                          const int* __restrict__ wid,
                                          const unsigned* __restrict__ wf,
                                          const float* __restrict__ al,
                                          const float* __restrict__ ar,
                                          unsigned* __restrict__ featb,
                                          float* __restrict__ el, float* __restrict__ er) {
    __shared__ unsigned hl[64 * 68];     // 17408 B
    int t = threadIdx.x;
    int n0 = bid * 64;
    if (IN_BF16) {
        const uint4* hb4 = (const uint4*)hin;
        #pragma unroll
        for (int r = 0; r < 4; ++r) {    // 1024 uint4 = 64 nodes x 16
            int i = t + 256 * r;
            int n = i >> 4, q = i & 15;
            uint4 v = {0u, 0u, 0u, 0u};
            int gn = n0 + n;
            if (gn < N_NODES) v = hb4[(size_t)gn * 16 + q];
            *(uint4*)&hl[n * 68 + q * 4] = v;
        }
    } else {
        const float4* h4 = (const float4*)hin;
        #pragma unroll
        for (int r = 0; r < 8; ++r) {    // 2048 float4 = 64 nodes x 32
            int i = t + 256 * r;
            int n = i >> 5, q4 = i & 31;
            float4 v = {0.f, 0.f, 0.f, 0.f};
            int gn = n0 + n;
            if (gn < N_NODES) {
                int row = wid ? wid[gn] : gn;
                v = h4[(size_t)row * 32 + q4];
            }
            hl[n * 68 + q4 * 2]     = pack_bf2(v.x, v.y);
            hl[n * 68 + q4 * 2 + 1] = pack_bf2(v.z, v.w);
        }
    }
    __syncthreads();
    int w = t >> 6, lane = t & 63;
    int col = lane & 15, quad = lane >> 4;
    int nbase = n0 + 16 * w;
    bf16x8 afr[4];
    #pragma unroll
    for (int kq = 0; kq < 4; ++kq)
        afr[kq] = *(const bf16x8*)&hl[(16 * w + col) * 68 + 16 * kq + 4 * quad];
    f32x4 acc[8];
    #pragma unroll
    for (int ct = 0; ct < 8; ++ct) acc[ct] = (f32x4){0.f, 0.f, 0.f, 0.f};
    const uint4* wf4 = (const uint4*)wf;
    #pragma unroll
    for (int ct = 0; ct < 8; ++ct) {
        #pragma unroll
        for (int kq = 0; kq < 4; ++kq) {
            uint4 braw = wf4[(ct * 4 + kq) * 64 + lane];
            bf16x8 bfr = *(const bf16x8*)&braw;
            acc[ct] = __builtin_amdgcn_mfma_f32_16x16x32_bf16(afr[kq], bfr, acc[ct], 0, 0, 0);
        }
    }
    #pragma unroll
    for (int ct = 0; ct < 8; ++ct) {
        #pragma unroll
        for (int reg = 0; reg < 4; ++reg) {
            float v = acc[ct][reg];
            float pv = __shfl_xor(v, 1, 64);
            int node = nbase + quad * 4 + reg;
            if (!(col & 1) && node < N_NODES)
                featb[(size_t)node * 64 + ct * 8 + (col >> 1)] = pack_bf2(v, pv);
        }
    }
    float alv[8], arv[8];
    #pragma unroll
    for (int ct = 0; ct < 8; ++ct) {
        alv[ct] = al[ct * 16 + col];
        arv[ct] = ar[ct * 16 + col];
    }
    #pragma unroll
    for (int reg = 0; reg < 4; ++reg) {
        int node = nbase + quad * 4 + reg;
        #pragma unroll
        for (int hd = 0; hd < 4; ++hd) {
            float pl = acc[2 * hd][reg] * alv[2 * hd] + acc[2 * hd + 1][reg] * alv[2 * hd + 1];
            float pr = acc[2 * hd][reg] * arv[2 * hd] + acc[2 * hd + 1][reg] * arv[2 * hd + 1];
            #pragma unroll
            for (int off = 1; off < 16; off <<= 1) {
                pl += __shfl_xor(pl, off, 64);
                pr += __shfl_xor(pr, off, 64);
            }
            if (col == hd && node < N_NODES) {
                el[node * 4 + hd] = pl * LOG2E;
                er[node * 4 + hd] = pr * LOG2E;
            }
        }
    }
}

template<int IN_BF16>
__global__ __launch_bounds__(256)
void feat_kernel_t(const void* __restrict__ hin, const int* __restrict__ wid,
                   const unsigned* __restrict__ wf,
                   const float* __restrict__ al, const float* __restrict__ ar,
                   unsigned* __restrict__ featb, float* __restrict__ el,
                   float* __restrict__ er) {
    feat_body<IN_BF16>(blockIdx.x, hin, wid, wf, al, ar, featb, el, er);
}

// scatter (CSR finalize) fused with layer-0 feat (independent work)
__global__ __launch_bounds__(256)
void scatter_feat0_kernel(const int* __restrict__ src, const int* __restrict__ dst,
                          const int* __restrict__ rank, const int* __restrict__ row_start,
                          int* __restrict__ csr_src,
                          const float* __restrict__ emb, const int* __restrict__ wid,
                          const unsigned* __restrict__ wf0,
                          const float* __restrict__ al0, const float* __restrict__ ar0,
                          unsigned* __restrict__ featb, float* __restrict__ el,
                          float* __restrict__ er) {
    if (blockIdx.x < EDGE_NB) {
        scatter_body(blockIdx.x, src, dst, rank, row_start, csr_src);
    } else {
        feat_body<0>(blockIdx.x - EDGE_NB, emb, wid, wf0, al0, ar0, featb, el, er);
    }
}

// Fused softmax + aggregation + ELU. One 64-lane wave per dst node.
template<int OUT_BF16>
__global__ void gat_aggregate_t(const int* __restrict__ row_start, const int* __restrict__ csr_src,
                                const unsigned* __restrict__ featb, const float* __restrict__ el,
                                const float* __restrict__ er, float* __restrict__ houtf,
                                unsigned* __restrict__ houtb) {
    int lane = threadIdx.x & 63;
    int d = blockIdx.x * 4 + (threadIdx.x >> 6);
    int beg = row_start[d], end = row_start[d + 1];
    int eg = lane >> 4;          // edge slot 0..3
    int li = lane & 15;          // channel group: channels [8li, 8li+8)
    int hc = li >> 2;            // head of these channels
    float er_h = er[d * 4 + hc];
    float a0 = 0.f, a1 = 0.f, a2 = 0.f, a3 = 0.f;
    float a4 = 0.f, a5 = 0.f, a6 = 0.f, a7 = 0.f;
    float dsum = 0.f;
    int b8 = beg + ((end - beg) & ~7);
    for (int base = beg; base < b8; base += 8) {
        int ea = base + eg, eb = base + 4 + eg;
        int sa = csr_src[ea];
        int sb = csr_src[eb];
        float la = el[sa * 4 + hc];
        float lb = el[sb * 4 + hc];
        uint4 pa = *(const uint4*)(featb + (size_t)sa * 64 + li * 4);
        uint4 pb = *(const uint4*)(featb + (size_t)sb * 64 + li * 4);
        float va = la + er_h; va = fmaxf(va, NEG_SLOPE * va);
        float vb = lb + er_h; vb = fmaxf(vb, NEG_SLOPE * vb);
        float xa = exp2f(va), xb = exp2f(vb);
        dsum += xa + xb;
        a0 += __uint_as_float(pa.x << 16) * xa;
        a1 += __uint_as_float(pa.x & 0xFFFF0000u) * xa;
        a2 += __uint_as_float(pa.y << 16) * xa;
        a3 += __uint_as_float(pa.y & 0xFFFF0000u) * xa;
        a4 += __uint_as_float(pa.z << 16) * xa;
        a5 += __uint_as_float(pa.z & 0xFFFF0000u) * xa;
        a6 += __uint_as_float(pa.w << 16) * xa;
        a7 += __uint_as_float(pa.w & 0xFFFF0000u) * xa;
        a0 += __uint_as_float(pb.x << 16) * xb;
        a1 += __uint_as_float(pb.x & 0xFFFF0000u) * xb;
        a2 += __uint_as_float(pb.y << 16) * xb;
        a3 += __uint_as_float(pb.y & 0xFFFF0000u) * xb;
        a4 += __uint_as_float(pb.z << 16) * xb;
        a5 += __uint_as_float(pb.z & 0xFFFF0000u) * xb;
        a6 += __uint_as_float(pb.w << 16) * xb;
        a7 += __uint_as_float(pb.w & 0xFFFF0000u) * xb;
    }
    for (int ee = b8 + eg; ee < end; ee += 4) {
        int s = csr_src[ee];
        float lv = el[s * 4 + hc];
        uint4 pv = *(const uint4*)(featb + (size_t)s * 64 + li * 4);
        float v = lv + er_h; v = fmaxf(v, NEG_SLOPE * v);
        float x = exp2f(v);
        dsum += x;
        a0 += __uint_as_float(pv.x << 16) * x;
        a1 += __uint_as_float(pv.x & 0xFFFF0000u) * x;
        a2 += __uint_as_float(pv.y << 16) * x;
        a3 += __uint_as_float(pv.y & 0xFFFF0000u) * x;
        a4 += __uint_as_float(pv.z << 16) * x;
        a5 += __uint_as_float(pv.z & 0xFFFF0000u) * x;
        a6 += __uint_as_float(pv.w << 16) * x;
        a7 += __uint_as_float(pv.w & 0xFFFF0000u) * x;
    }
    #pragma unroll
    for (int off = 16; off < 64; off <<= 1) {
        a0 += __shfl_xor(a0, off, 64);
        a1 += __shfl_xor(a1, off, 64);
        a2 += __shfl_xor(a2, off, 64);
        a3 += __shfl_xor(a3, off, 64);
        a4 += __shfl_xor(a4, off, 64);
        a5 += __shfl_xor(a5, off, 64);
        a6 += __shfl_xor(a6, off, 64);
        a7 += __shfl_xor(a7, off, 64);
        dsum += __shfl_xor(dsum, off, 64);
    }
    if (eg == 0) {
        float inv = 1.f / (dsum + 1e-10f);
        float o0 = a0 * inv, o1 = a1 * inv, o2 = a2 * inv, o3 = a3 * inv;
        float o4 = a4 * inv, o5 = a5 * inv, o6 = a6 * inv, o7 = a7 * inv;
        o0 = o0 > 0.f ? o0 : expm1f(o0);
        o1 = o1 > 0.f ? o1 : expm1f(o1);
        o2 = o2 > 0.f ? o2 : expm1f(o2);
        o3 = o3 > 0.f ? o3 : expm1f(o3);
        o4 = o4 > 0.f ? o4 : expm1f(o4);
        o5 = o5 > 0.f ? o5 : expm1f(o5);
        o6 = o6 > 0.f ? o6 : expm1f(o6);
        o7 = o7 > 0.f ? o7 : expm1f(o7);
        if (OUT_BF16) {
            uint4 wv;
            wv.x = pack_bf2(o0, o1);
            wv.y = pack_bf2(o2, o3);
            wv.z = pack_bf2(o4, o5);
            wv.w = pack_bf2(o6, o7);
            ((uint4*)(houtb + (size_t)d * 64))[li] = wv;
        } else {
            float4* op = (float4*)(houtf + (size_t)d * 128);
            float4 w0 = {o0, o1, o2, o3};
            float4 w1 = {o4, o5, o6, o7};
            op[li * 2] = w0;
            op[li * 2 + 1] = w1;
        }
    }
}

// ---------------- pooling / loss ----------------

__global__ void pool_kernel(const int* __restrict__ gid, const float* __restrict__ h,
                            unsigned* __restrict__ pkeys) {
    int t = threadIdx.x;
    int c = t & 127;
    int par = t >> 7;              // 0/1
    int n0 = blockIdx.x * POOL_CHUNK;
    float m = 0.f;
    int cur_g = -1;
    for (int n = n0 + par; n < n0 + POOL_CHUNK; n += 2) {
        int g = gid[n];
        if (g != cur_g) {
            if (cur_g >= 0) atomicMax(&pkeys[cur_g * 128 + c], fkey(m));
            cur_g = g;
            m = -3.0e38f;
        }
        m = fmaxf(m, h[(size_t)n * 128 + c]);
    }
    if (cur_g >= 0) atomicMax(&pkeys[cur_g * 128 + c], fkey(m));
}

// logits + loss fused: one block, 4 waves.
__global__ void logits_final_kernel(const unsigned* __restrict__ pkeys,
                                    const float* __restrict__ w, const float* __restrict__ bptr,
                                    const float* __restrict__ y, float* __restrict__ out) {
    __shared__ float slog[N_GRAPHS];
    int t = threadIdx.x;
    int wv = t >> 6, lane = t & 63;
    float b = bptr[0];
    #pragma unroll
    for (int k = 0; k < 16; ++k) {
        int g = wv * 16 + k;
        float sum = 0.f;
        #pragma unroll
        for (int c0 = 0; c0 < 128; c0 += 64) {
            int c = c0 + lane;
            unsigned kk = pkeys[g * 128 + c];
            float v = (kk == 0u) ? 0.f : kval(kk);
            sum += v * w[c];
        }
        #pragma unroll
        for (int off = 32; off; off >>= 1) sum += __shfl_down(sum, off, 64);
        if (lane == 0) slog[g] = sum + b;
    }
    __syncthreads();
    if (t < N_GRAPHS) {
        float l = slog[t];
        float term = fmaxf(l, 0.f) - l * y[t] + log1pf(expf(-fabsf(l)));
        float s = term;
        #pragma unroll
        for (int off = 32; off; off >>= 1) s += __shfl_down(s, off, 64);
        out[1 + t] = 1.f / (1.f + expf(-l));
        if (t == 0) out[0] = s * (1.f / 64.f);
    }
}

extern "C" void kernel_launch(void* const* d_in, const int* in_sizes, int n_in,
                              void* d_out, int out_size, void* d_ws, size_t ws_size,
                              hipStream_t stream) {
    const int* word_ids  = (const int*)d_in[0];
    const int* esrc      = (const int*)d_in[1];
    const int* edst      = (const int*)d_in[2];
    const int* gid       = (const int*)d_in[3];
    const float* y_data  = (const float*)d_in[4];
    const float* emb     = (const float*)d_in[5];
    const float* W0      = (const float*)d_in[6];
    const float* al0     = (const float*)d_in[7];
    const float* ar0     = (const float*)d_in[8];
    const float* W1      = (const float*)d_in[9];
    const float* al1     = (const float*)d_in[10];
    const float* ar1     = (const float*)d_in[11];
    const float* out_w   = (const float*)d_in[12];
    const float* out_b   = (const float*)d_in[13];
    float* out = (float*)d_out;

    // workspace layout (float offsets)
    float* ws = (float*)d_ws;
    unsigned* featb  = (unsigned*)ws;                // N*64 uints = 3,200,000
    unsigned* hb     = (unsigned*)(ws + 3200000);    // N*64 uints (bf16 layer0 out)
    float*    hout   = ws + 6400000;                 // N*128 f32 (layer1 out)
    float*    el     = ws + 12800000;                // 200,000
    float*    er     = ws + 13000000;                // 200,000
    int*      row_st = (int*)(ws + 13200000);        // 50,001 (pad to 50,004)
    int*      deg    = (int*)(ws + 13250004);        // 50,000
    int*      rank   = (int*)(ws + 13300004);        // 800,000
    int*      csrsrc = (int*)(ws + 14100004);        // 800,000
    int*      partial= (int*)(ws + 14900004);        // 196 (pad to 200)
    unsigned* pkeys  = (unsigned*)(ws + 14900204);   // 8,192
    unsigned* wf0    = (unsigned*)(ws + 14908396);   // 8,192 uints (16B-aligned)
    unsigned* wf1    = (unsigned*)(ws + 14916588);   // 8,192 uints
    int*      deg2   = (int*)(ws + 14924780);        // 50,000 (probe scratch)
    int*      rank2  = (int*)(ws + 14974780);        // 800,000 (probe scratch)

    // prep (W-frags, deg/deg2/pkeys zero) then CSR counting
    prep_kernel<<<16 + 2 * SCAN_NB + 32, 256, 0, stream>>>(W0, W1, wf0, wf1, deg, deg2, pkeys);
    hist_kernel<<<EDGE_NB, 256, 0, stream>>>(edst, deg, rank);
    // PROBE: hist clone into scratch (side-effect-free) — prices atomic cost
    hist_kernel<<<EDGE_NB, 256, 0, stream>>>(edst, deg2, rank2);
    partial_kernel<<<SCAN_NB, 256, 0, stream>>>(deg, partial);
    csr_offsets_kernel<<<SCAN_NB, 256, 0, stream>>>(deg, partial, row_st);

    scatter_feat0_kernel<<<EDGE_NB + FEAT_NB, 256, 0, stream>>>(
        esrc, edst, rank, row_st, csrsrc, emb, word_ids, wf0, al0, ar0, featb, el, er);
    // PROBE: sf0 clone (idempotent rewrite)
    scatter_feat0_kernel<<<EDGE_NB + FEAT_NB, 256, 0, stream>>>(
        esrc, edst, rank, row_st, csrsrc, emb, word_ids, wf0, al0, ar0, featb, el, er);

    gat_aggregate_t<1><<<12500, 256, 0, stream>>>(row_st, csrsrc, featb, el, er, nullptr, hb);
    feat_kernel_t<1><<<FEAT_NB, 256, 0, stream>>>(hb, nullptr, wf1, al1, ar1, featb, el, er);
    // PROBE: feat1 clone (idempotent rewrite)
    feat_kernel_t<1><<<FEAT_NB, 256, 0, stream>>>(hb, nullptr, wf1, al1, ar1, featb, el, er);
    gat_aggregate_t<0><<<12500, 256, 0, stream>>>(row_st, csrsrc, featb, el, er, hout, nullptr);

    pool_kernel<<<POOL_NB, 256, 0, stream>>>(gid, hout, pkeys);
    // PROBE: pool clone (atomicMax idempotent)
    pool_kernel<<<POOL_NB, 256, 0, stream>>>(gid, hout, pkeys);
    logits_final_kernel<<<1, 256, 0, stream>>>(pkeys, out_w, out_b, y_data, out);
}

// Round 5
// 384.427 us; speedup vs baseline: 1.0346x; 1.0346x over previous
//
#include <hip/hip_runtime.h>
#include <math.h>

#define N_NODES 50000
#define N_EDGES 800000
#define HEADS 4
#define N_GRAPHS 64
#define NEG_SLOPE 0.2f
#define LOG2E 1.4426950408889634f
#define SCAN_NB 196            // 196*256 = 50176 >= N_NODES
#define POOL_CHUNK 50
#define POOL_NB 1000           // 1000*50 = 50000 exactly
#define FEAT_NB 782            // ceil(50000/64)
#define AGG_NB 12500           // 12500*4 = 50000 dst nodes (per head pass)
#define EDGE_Q 200000          // N_EDGES/4: 4 edges per thread
#define EDGE_NB 782            // ceil(200000/256)

typedef __attribute__((ext_vector_type(8))) short bf16x8;
typedef __attribute__((ext_vector_type(4))) float f32x4;

// monotone float<->uint key for atomicMax-based segment max (pooling).
__device__ __forceinline__ unsigned fkey(float f) {
    unsigned u = __float_as_uint(f);
    return (u & 0x80000000u) ? ~u : (u | 0x80000000u);
}
__device__ __forceinline__ float kval(unsigned k) {
    unsigned u = (k & 0x80000000u) ? (k & 0x7FFFFFFFu) : ~k;
    return __uint_as_float(u);
}

// f32 -> bf16 (RNE), two packed into one uint (lo = first channel)
__device__ __forceinline__ unsigned short f2bf(float f) {
    unsigned u = __float_as_uint(f);
    u += 0x7FFFu + ((u >> 16) & 1u);
    return (unsigned short)(u >> 16);
}
__device__ __forceinline__ unsigned pack_bf2(float a, float b) {
    return (unsigned)f2bf(a) | ((unsigned)f2bf(b) << 16);
}

// ---------------- CSR build (counting sort by dst, rank-based) ----------------

__global__ void hist_kernel(const int* __restrict__ dst, int* __restrict__ deg,
                            int* __restrict__ rank) {
    int i = blockIdx.x * 256 + threadIdx.x;
    if (i >= EDGE_Q) return;
    int e0 = i, e1 = i + EDGE_Q, e2 = i + 2 * EDGE_Q, e3 = i + 3 * EDGE_Q;
    int d0 = dst[e0], d1 = dst[e1], d2 = dst[e2], d3 = dst[e3];
    int r0 = atomicAdd(&deg[d0], 1);
    int r1 = atomicAdd(&deg[d1], 1);
    int r2 = atomicAdd(&deg[d2], 1);
    int r3 = atomicAdd(&deg[d3], 1);
    rank[e0] = r0; rank[e1] = r1; rank[e2] = r2; rank[e3] = r3;
}

__global__ void partial_kernel(const int* __restrict__ deg, int* __restrict__ partial) {
    int t = threadIdx.x, b = blockIdx.x;
    int i = b * 256 + t;
    int v = (i < N_NODES) ? deg[i] : 0;
    #pragma unroll
    for (int off = 1; off < 64; off <<= 1) v += __shfl_xor(v, off, 64);
    __shared__ int wsum[4];
    if ((t & 63) == 0) wsum[t >> 6] = v;
    __syncthreads();
    if (t == 0) partial[b] = wsum[0] + wsum[1] + wsum[2] + wsum[3];
}

__global__ void csr_offsets_kernel(const int* __restrict__ deg, const int* __restrict__ partial,
                                   int* __restrict__ row_start) {
    __shared__ int sb[SCAN_NB];
    __shared__ int wsumA[4];
    __shared__ int wsumB[4];
    int t = threadIdx.x, b = blockIdx.x;
    int lane = t & 63, w = t >> 6;
    {   // exclusive scan of partial -> sb
        int v = (t < SCAN_NB) ? partial[t] : 0;
        int incl = v;
        #pragma unroll
        for (int off = 1; off < 64; off <<= 1) {
            int u = __shfl_up(incl, off, 64);
            if (lane >= off) incl += u;
        }
        if (lane == 63) wsumA[w] = incl;
        __syncthreads();
        int woff = 0;
        #pragma unroll
        for (int k = 0; k < 4; ++k) if (k < w) woff += wsumA[k];
        if (t < SCAN_NB) sb[t] = woff + incl - v;
        __syncthreads();
    }
    int i = b * 256 + t;
    int v = (i < N_NODES) ? deg[i] : 0;
    int incl = v;
    #pragma unroll
    for (int off = 1; off < 64; off <<= 1) {
        int u = __shfl_up(incl, off, 64);
        if (lane >= off) incl += u;
    }
    if (lane == 63) wsumB[w] = incl;
    __syncthreads();
    int woff = sb[b];
    #pragma unroll
    for (int k = 0; k < 4; ++k) if (k < w) woff += wsumB[k];
    int excl = woff + incl - v;
    if (i < N_NODES) row_start[i] = excl;
    else if (i == N_NODES) row_start[i] = excl;   // == N_EDGES
}

__device__ __forceinline__ void scatter_body(int bid, const int* __restrict__ src,
                                             const int* __restrict__ dst,
                                             const int* __restrict__ rank,
                                             const int* __restrict__ row_start,
                                             int* __restrict__ csr_src) {
    int i = bid * 256 + threadIdx.x;
    if (i >= EDGE_Q) return;
    int e0 = i, e1 = i + EDGE_Q, e2 = i + 2 * EDGE_Q, e3 = i + 3 * EDGE_Q;
    int d0 = dst[e0], d1 = dst[e1], d2 = dst[e2], d3 = dst[e3];
    int k0 = rank[e0], k1 = rank[e1], k2 = rank[e2], k3 = rank[e3];
    int s0 = src[e0], s1 = src[e1], s2 = src[e2], s3 = src[e3];
    csr_src[row_start[d0] + k0] = s0;
    csr_src[row_start[d1] + k1] = s1;
    csr_src[row_start[d2] + k2] = s2;
    csr_src[row_start[d3] + k3] = s3;
}

// ---------------- node pipeline ----------------

// Pre-pack W into MFMA B-fragment lane order (bf16).
__device__ __forceinline__ void wfrag_body(const float* __restrict__ W,
                                           unsigned* __restrict__ wf, int slot) {
    int f = slot >> 6, l = slot & 63;
    int n = l & 15, q = l >> 4;
    int ct = f >> 2, kq = f & 3;
    int col = 16 * ct + n;
    int k0 = 32 * kq + 8 * q;
    uint4 o;
    o.x = pack_bf2(W[(k0 + 0) * 128 + col], W[(k0 + 1) * 128 + col]);
    o.y = pack_bf2(W[(k0 + 2) * 128 + col], W[(k0 + 3) * 128 + col]);
    o.z = pack_bf2(W[(k0 + 4) * 128 + col], W[(k0 + 5) * 128 + col]);
    o.w = pack_bf2(W[(k0 + 6) * 128 + col], W[(k0 + 7) * 128 + col]);
    ((uint4*)wf)[slot] = o;
}

// prep: both W-frag packs + zero deg + zero pkeys, one launch.
__global__ void prep_kernel(const float* __restrict__ W0, const float* __restrict__ W1,
                            unsigned* __restrict__ wf0, unsigned* __restrict__ wf1,
                            int* __restrict__ deg, unsigned* __restrict__ pkeys) {
    int b = blockIdx.x, t = threadIdx.x;
    if (b < 8) {
        wfrag_body(W0, wf0, b * 256 + t);
    } else if (b < 16) {
        wfrag_body(W1, wf1, (b - 8) * 256 + t);
    } else if (b < 16 + SCAN_NB) {
        int i = (b - 16) * 256 + t;
        if (i < N_NODES) deg[i] = 0;
    } else {
        int i = (b - 16 - SCAN_NB) * 256 + t;
        if (i < N_GRAPHS * 128) pkeys[i] = 0;
    }
}

// feat = h @ W via MFMA 16x16x32 bf16. 64 nodes/block, 4 waves.
// featb layout is HEAD-QUARTERED: featb[((head*N + node)*16) + u], u in [0,16)
// uints covering head's 32 channels in pair order (head = ct>>1).
// IN_BF16=1: h is head-quartered bf16 (hb layout, same as featb).
// IN_BF16=0: h is f32 [N,128] (optionally gathered via wid).
template<int IN_BF16>
__device__ __forceinline__ void feat_body(int bid, const void* __restrict__ hin,
                                          const int* __restrict__ wid,
                                          const unsigned* __restrict__ wf,
                                          const float* __restrict__ al,
                                          const float* __restrict__ ar,
                                          unsigned* __restrict__ featb,
                                          float* __restrict__ el, float* __restrict__ er) {
    __shared__ unsigned hl[64 * 68];     // 17408 B
    int t = threadIdx.x;
    int n0 = bid * 64;
    if (IN_BF16) {
        const uint4* hb4 = (const uint4*)hin;
        #pragma unroll
        for (int r = 0; r < 4; ++r) {    // 1024 uint4 = 64 nodes x 16
            int i = t + 256 * r;
            int n = i >> 4, qq = i & 15;   // qq: uint4 index in full row
            uint4 v = {0u, 0u, 0u, 0u};
            int gn = n0 + n;
            if (gn < N_NODES)
                v = hb4[((size_t)(qq >> 2) * N_NODES + gn) * 4 + (qq & 3)];
            *(uint4*)&hl[n * 68 + qq * 4] = v;
        }
    } else {
        const float4* h4 = (const float4*)hin;
        #pragma unroll
        for (int r = 0; r < 8; ++r) {    // 2048 float4 = 64 nodes x 32
            int i = t + 256 * r;
            int n = i >> 5, q4 = i & 31;
            float4 v = {0.f, 0.f, 0.f, 0.f};
            int gn = n0 + n;
            if (gn < N_NODES) {
                int row = wid ? wid[gn] : gn;
                v = h4[(size_t)row * 32 + q4];
            }
            hl[n * 68 + q4 * 2]     = pack_bf2(v.x, v.y);
            hl[n * 68 + q4 * 2 + 1] = pack_bf2(v.z, v.w);
        }
    }
    __syncthreads();
    int w = t >> 6, lane = t & 63;
    int col = lane & 15, quad = lane >> 4;
    int nbase = n0 + 16 * w;
    bf16x8 afr[4];
    #pragma unroll
    for (int kq = 0; kq < 4; ++kq)
        afr[kq] = *(const bf16x8*)&hl[(16 * w + col) * 68 + 16 * kq + 4 * quad];
    f32x4 acc[8];
    #pragma unroll
    for (int ct = 0; ct < 8; ++ct) acc[ct] = (f32x4){0.f, 0.f, 0.f, 0.f};
    const uint4* wf4 = (const uint4*)wf;
    #pragma unroll
    for (int ct = 0; ct < 8; ++ct) {
        #pragma unroll
        for (int kq = 0; kq < 4; ++kq) {
            uint4 braw = wf4[(ct * 4 + kq) * 64 + lane];
            bf16x8 bfr = *(const bf16x8*)&braw;
            acc[ct] = __builtin_amdgcn_mfma_f32_16x16x32_bf16(afr[kq], bfr, acc[ct], 0, 0, 0);
        }
    }
    // featb write (head-quartered): head = ct>>1, uint = (ct&1)*8 + (col>>1)
    #pragma unroll
    for (int ct = 0; ct < 8; ++ct) {
        #pragma unroll
        for (int reg = 0; reg < 4; ++reg) {
            float v = acc[ct][reg];
            float pv = __shfl_xor(v, 1, 64);
            int node = nbase + quad * 4 + reg;
            if (!(col & 1) && node < N_NODES)
                featb[((size_t)(ct >> 1) * N_NODES + node) * 16 + (ct & 1) * 8 + (col >> 1)]
                    = pack_bf2(v, pv);
        }
    }
    float alv[8], arv[8];
    #pragma unroll
    for (int ct = 0; ct < 8; ++ct) {
        alv[ct] = al[ct * 16 + col];
        arv[ct] = ar[ct * 16 + col];
    }
    #pragma unroll
    for (int reg = 0; reg < 4; ++reg) {
        int node = nbase + quad * 4 + reg;
        #pragma unroll
        for (int hd = 0; hd < 4; ++hd) {
            float pl = acc[2 * hd][reg] * alv[2 * hd] + acc[2 * hd + 1][reg] * alv[2 * hd + 1];
            float pr = acc[2 * hd][reg] * arv[2 * hd] + acc[2 * hd + 1][reg] * arv[2 * hd + 1];
            #pragma unroll
            for (int off = 1; off < 16; off <<= 1) {
                pl += __shfl_xor(pl, off, 64);
                pr += __shfl_xor(pr, off, 64);
            }
            if (col == hd && node < N_NODES) {
                el[node * 4 + hd] = pl * LOG2E;
                er[node * 4 + hd] = pr * LOG2E;
            }
        }
    }
}

template<int IN_BF16>
__global__ __launch_bounds__(256)
void feat_kernel_t(const void* __restrict__ hin, const int* __restrict__ wid,
                   const unsigned* __restrict__ wf,
                   const float* __restrict__ al, const float* __restrict__ ar,
                   unsigned* __restrict__ featb, float* __restrict__ el,
                   float* __restrict__ er) {
    feat_body<IN_BF16>(blockIdx.x, hin, wid, wf, al, ar, featb, el, er);
}

// scatter (CSR finalize) fused with layer-0 feat (independent work)
__global__ __launch_bounds__(256)
void scatter_feat0_kernel(const int* __restrict__ src, const int* __restrict__ dst,
                          const int* __restrict__ rank, const int* __restrict__ row_start,
                          int* __restrict__ csr_src,
                          const float* __restrict__ emb, const int* __restrict__ wid,
                          const unsigned* __restrict__ wf0,
                          const float* __restrict__ al0, const float* __restrict__ ar0,
                          unsigned* __restrict__ featb, float* __restrict__ el,
                          float* __restrict__ er) {
    if (blockIdx.x < EDGE_NB) {
        scatter_body(blockIdx.x, src, dst, rank, row_start, csr_src);
    } else {
        feat_body<0>(blockIdx.x - EDGE_NB, emb, wid, wf0, al0, ar0, featb, el, er);
    }
}

// Head-split fused softmax + aggregation + ELU. One wave per (dst, head).
// blocks [q*AGG_NB, (q+1)*AGG_NB) handle head q (x-major dispatch keeps the
// 3.2 MB per-head featb slice L2-resident during its pass wave).
// 4 lanes per edge (li = uint4 slot, 8 channels), 16 edges per wave-iter.
// OUT_BF16=1: write head-quartered bf16 rows (hb layout = featb layout).
// OUT_BF16=0: write f32 node-major [node][128] (channels q*32 + li*8 ..).
template<int OUT_BF16>
__global__ void gat_aggregate_q(const int* __restrict__ row_start, const int* __restrict__ csr_src,
                                const unsigned* __restrict__ featb, const float* __restrict__ el,
                                const float* __restrict__ er, float* __restrict__ houtf,
                                unsigned* __restrict__ houtb) {
    int bid = blockIdx.x;
    int q = bid / AGG_NB;                  // head
    int db = bid - q * AGG_NB;
    int lane = threadIdx.x & 63;
    int d = db * 4 + (threadIdx.x >> 6);
    int beg = row_start[d], end = row_start[d + 1];
    int eg = lane >> 2;                    // edge slot 0..15
    int li = lane & 3;                     // uint4 slot: channels [8li, 8li+8) of head q
    float er_h = er[d * 4 + q];
    const unsigned* fq = featb + (size_t)q * N_NODES * 16;
    float a0 = 0.f, a1 = 0.f, a2 = 0.f, a3 = 0.f;
    float a4 = 0.f, a5 = 0.f, a6 = 0.f, a7 = 0.f;
    float dsum = 0.f;
    int b16 = beg + ((end - beg) & ~15);
    for (int base = beg; base < b16; base += 16) {
        int s = csr_src[base + eg];
        float lv = el[s * 4 + q];
        uint4 pv = *(const uint4*)(fq + (size_t)s * 16 + li * 4);
        float v = lv + er_h; v = fmaxf(v, NEG_SLOPE * v);
        float x = exp2f(v);
        dsum += x;
        a0 += __uint_as_float(pv.x << 16) * x;
        a1 += __uint_as_float(pv.x & 0xFFFF0000u) * x;
        a2 += __uint_as_float(pv.y << 16) * x;
        a3 += __uint_as_float(pv.y & 0xFFFF0000u) * x;
        a4 += __uint_as_float(pv.z << 16) * x;
        a5 += __uint_as_float(pv.z & 0xFFFF0000u) * x;
        a6 += __uint_as_float(pv.w << 16) * x;
        a7 += __uint_as_float(pv.w & 0xFFFF0000u) * x;
    }
    for (int ee = b16 + eg; ee < end; ee += 16) {
        int s = csr_src[ee];
        float lv = el[s * 4 + q];
        uint4 pv = *(const uint4*)(fq + (size_t)s * 16 + li * 4);
        float v = lv + er_h; v = fmaxf(v, NEG_SLOPE * v);
        float x = exp2f(v);
        dsum += x;
        a0 += __uint_as_float(pv.x << 16) * x;
        a1 += __uint_as_float(pv.x & 0xFFFF0000u) * x;
        a2 += __uint_as_float(pv.y << 16) * x;
        a3 += __uint_as_float(pv.y & 0xFFFF0000u) * x;
        a4 += __uint_as_float(pv.z << 16) * x;
        a5 += __uint_as_float(pv.z & 0xFFFF0000u) * x;
        a6 += __uint_as_float(pv.w << 16) * x;
        a7 += __uint_as_float(pv.w & 0xFFFF0000u) * x;
    }
    // reduce over edge-slot bits (lane bits 2..5)
    #pragma unroll
    for (int off = 4; off < 64; off <<= 1) {
        a0 += __shfl_xor(a0, off, 64);
        a1 += __shfl_xor(a1, off, 64);
        a2 += __shfl_xor(a2, off, 64);
        a3 += __shfl_xor(a3, off, 64);
        a4 += __shfl_xor(a4, off, 64);
        a5 += __shfl_xor(a5, off, 64);
        a6 += __shfl_xor(a6, off, 64);
        a7 += __shfl_xor(a7, off, 64);
        dsum += __shfl_xor(dsum, off, 64);
    }
    if (eg == 0) {
        float inv = 1.f / (dsum + 1e-10f);
        float o0 = a0 * inv, o1 = a1 * inv, o2 = a2 * inv, o3 = a3 * inv;
        float o4 = a4 * inv, o5 = a5 * inv, o6 = a6 * inv, o7 = a7 * inv;
        o0 = o0 > 0.f ? o0 : expm1f(o0);
        o1 = o1 > 0.f ? o1 : expm1f(o1);
        o2 = o2 > 0.f ? o2 : expm1f(o2);
        o3 = o3 > 0.f ? o3 : expm1f(o3);
        o4 = o4 > 0.f ? o4 : expm1f(o4);
        o5 = o5 > 0.f ? o5 : expm1f(o5);
        o6 = o6 > 0.f ? o6 : expm1f(o6);
        o7 = o7 > 0.f ? o7 : expm1f(o7);
        if (OUT_BF16) {
            uint4 wv;
            wv.x = pack_bf2(o0, o1);
            wv.y = pack_bf2(o2, o3);
            wv.z = pack_bf2(o4, o5);
            wv.w = pack_bf2(o6, o7);
            ((uint4*)(houtb + ((size_t)q * N_NODES + d) * 16))[li] = wv;
        } else {
            float4* op = (float4*)(houtf + (size_t)d * 128 + q * 32 + li * 8);
            float4 w0 = {o0, o1, o2, o3};
            float4 w1 = {o4, o5, o6, o7};
            op[0] = w0;
            op[1] = w1;
        }
    }
}

// ---------------- pooling / loss ----------------

__global__ void pool_kernel(const int* __restrict__ gid, const float* __restrict__ h,
                            unsigned* __restrict__ pkeys) {
    int t = threadIdx.x;
    int c = t & 127;
    int par = t >> 7;              // 0/1
    int n0 = blockIdx.x * POOL_CHUNK;
    float m = 0.f;
    int cur_g = -1;
    for (int n = n0 + par; n < n0 + POOL_CHUNK; n += 2) {
        int g = gid[n];
        if (g != cur_g) {
            if (cur_g >= 0) atomicMax(&pkeys[cur_g * 128 + c], fkey(m));
            cur_g = g;
            m = -3.0e38f;
        }
        m = fmaxf(m, h[(size_t)n * 128 + c]);
    }
    if (cur_g >= 0) atomicMax(&pkeys[cur_g * 128 + c], fkey(m));
}

// logits + loss fused: one block, 4 waves.
__global__ void logits_final_kernel(const unsigned* __restrict__ pkeys,
                                    const float* __restrict__ w, const float* __restrict__ bptr,
                                    const float* __restrict__ y, float* __restrict__ out) {
    __shared__ float slog[N_GRAPHS];
    int t = threadIdx.x;
    int wv = t >> 6, lane = t & 63;
    float b = bptr[0];
    #pragma unroll
    for (int k = 0; k < 16; ++k) {
        int g = wv * 16 + k;
        float sum = 0.f;
        #pragma unroll
        for (int c0 = 0; c0 < 128; c0 += 64) {
            int c = c0 + lane;
            unsigned kk = pkeys[g * 128 + c];
            float v = (kk == 0u) ? 0.f : kval(kk);
            sum += v * w[c];
        }
        #pragma unroll
        for (int off = 32; off; off >>= 1) sum += __shfl_down(sum, off, 64);
        if (lane == 0) slog[g] = sum + b;
    }
    __syncthreads();
    if (t < N_GRAPHS) {
        float l = slog[t];
        float term = fmaxf(l, 0.f) - l * y[t] + log1pf(expf(-fabsf(l)));
        float s = term;
        #pragma unroll
        for (int off = 32; off; off >>= 1) s += __shfl_down(s, off, 64);
        out[1 + t] = 1.f / (1.f + expf(-l));
        if (t == 0) out[0] = s * (1.f / 64.f);
    }
}

extern "C" void kernel_launch(void* const* d_in, const int* in_sizes, int n_in,
                              void* d_out, int out_size, void* d_ws, size_t ws_size,
                              hipStream_t stream) {
    const int* word_ids  = (const int*)d_in[0];
    const int* esrc      = (const int*)d_in[1];
    const int* edst      = (const int*)d_in[2];
    const int* gid       = (const int*)d_in[3];
    const float* y_data  = (const float*)d_in[4];
    const float* emb     = (const float*)d_in[5];
    const float* W0      = (const float*)d_in[6];
    const float* al0     = (const float*)d_in[7];
    const float* ar0     = (const float*)d_in[8];
    const float* W1      = (const float*)d_in[9];
    const float* al1     = (const float*)d_in[10];
    const float* ar1     = (const float*)d_in[11];
    const float* out_w   = (const float*)d_in[12];
    const float* out_b   = (const float*)d_in[13];
    float* out = (float*)d_out;

    // workspace layout (float offsets)
    float* ws = (float*)d_ws;
    unsigned* featb  = (unsigned*)ws;                // 4 heads x N x 16 uints = 3,200,000
    unsigned* hb     = (unsigned*)(ws + 3200000);    // same layout (bf16 layer0 out)
    float*    hout   = ws + 6400000;                 // N*128 f32 (layer1 out)
    float*    el     = ws + 12800000;                // 200,000
    float*    er     = ws + 13000000;                // 200,000
    int*      row_st = (int*)(ws + 13200000);        // 50,001 (pad to 50,004)
    int*      deg    = (int*)(ws + 13250004);        // 50,000
    int*      rank   = (int*)(ws + 13300004);        // 800,000
    int*      csrsrc = (int*)(ws + 14100004);        // 800,000
    int*      partial= (int*)(ws + 14900004);        // 196 (pad to 200)
    unsigned* pkeys  = (unsigned*)(ws + 14900204);   // 8,192
    unsigned* wf0    = (unsigned*)(ws + 14908396);   // 8,192 uints (16B-aligned)
    unsigned* wf1    = (unsigned*)(ws + 14916588);   // 8,192 uints

    // prep (W-frags, deg/pkeys zero) then CSR counting
    prep_kernel<<<16 + SCAN_NB + 32, 256, 0, stream>>>(W0, W1, wf0, wf1, deg, pkeys);
    hist_kernel<<<EDGE_NB, 256, 0, stream>>>(edst, deg, rank);
    partial_kernel<<<SCAN_NB, 256, 0, stream>>>(deg, partial);
    csr_offsets_kernel<<<SCAN_NB, 256, 0, stream>>>(deg, partial, row_st);

    // CSR scatter fused with layer-0 feat (independent work)
    scatter_feat0_kernel<<<EDGE_NB + FEAT_NB, 256, 0, stream>>>(
        esrc, edst, rank, row_st, csrsrc, emb, word_ids, wf0, al0, ar0, featb, el, er);

    // layer 0 aggregate (head-split) -> head-quartered bf16; layer 1
    gat_aggregate_q<1><<<4 * AGG_NB, 256, 0, stream>>>(row_st, csrsrc, featb, el, er, nullptr, hb);
    feat_kernel_t<1><<<FEAT_NB, 256, 0, stream>>>(hb, nullptr, wf1, al1, ar1, featb, el, er);
    gat_aggregate_q<0><<<4 * AGG_NB, 256, 0, stream>>>(row_st, csrsrc, featb, el, er, hout, nullptr);

    pool_kernel<<<POOL_NB, 256, 0, stream>>>(gid, hout, pkeys);
    logits_final_kernel<<<1, 256, 0, stream>>>(pkeys, out_w, out_b, y_data, out);
}

// Round 6
// 311.320 us; speedup vs baseline: 1.2775x; 1.2348x over previous
//
#include <hip/hip_runtime.h>
#include <math.h>

#define N_NODES 50000
#define N_EDGES 800000
#define HEADS 4
#define N_GRAPHS 64
#define NEG_SLOPE 0.2f
#define LOG2E 1.4426950408889634f
#define SCAN_NB 196            // 196*256 = 50176 >= N_NODES
#define POOL_CHUNK 50
#define POOL_NB 1000           // 1000*50 = 50000 exactly
#define FEAT_NB 782            // ceil(50000/64)
#define EDGE_Q 200000          // N_EDGES/4: 4 edges per thread
#define EDGE_NB 782            // ceil(200000/256)

typedef __attribute__((ext_vector_type(8))) short bf16x8;
typedef __attribute__((ext_vector_type(4))) float f32x4;

// monotone float<->uint key for atomicMax-based segment max (pooling).
__device__ __forceinline__ unsigned fkey(float f) {
    unsigned u = __float_as_uint(f);
    return (u & 0x80000000u) ? ~u : (u | 0x80000000u);
}
__device__ __forceinline__ float kval(unsigned k) {
    unsigned u = (k & 0x80000000u) ? (k & 0x7FFFFFFFu) : ~k;
    return __uint_as_float(u);
}

// f32 -> bf16 (RNE), two packed into one uint (lo = first channel)
__device__ __forceinline__ unsigned short f2bf(float f) {
    unsigned u = __float_as_uint(f);
    u += 0x7FFFu + ((u >> 16) & 1u);
    return (unsigned short)(u >> 16);
}
__device__ __forceinline__ unsigned pack_bf2(float a, float b) {
    return (unsigned)f2bf(a) | ((unsigned)f2bf(b) << 16);
}

// cheap ELU: o>0 ? o : exp(o)-1 via exp2 (saves ~10 inst vs expm1f; abs err ~1e-8)
__device__ __forceinline__ float elu_fast(float o) {
    float e = exp2f(o * LOG2E) - 1.f;
    return o > 0.f ? o : e;
}

// ---------------- CSR build (counting sort by dst, cursor-based) ----------------

// hist: non-returning atomics (no rank array)
__global__ void hist_kernel(const int* __restrict__ dst, int* __restrict__ deg) {
    int i = blockIdx.x * 256 + threadIdx.x;
    if (i >= EDGE_Q) return;
    int d0 = dst[i], d1 = dst[i + EDGE_Q], d2 = dst[i + 2 * EDGE_Q], d3 = dst[i + 3 * EDGE_Q];
    atomicAdd(&deg[d0], 1);
    atomicAdd(&deg[d1], 1);
    atomicAdd(&deg[d2], 1);
    atomicAdd(&deg[d3], 1);
}

__global__ void partial_kernel(const int* __restrict__ deg, int* __restrict__ partial) {
    int t = threadIdx.x, b = blockIdx.x;
    int i = b * 256 + t;
    int v = (i < N_NODES) ? deg[i] : 0;
    #pragma unroll
    for (int off = 1; off < 64; off <<= 1) v += __shfl_xor(v, off, 64);
    __shared__ int wsum[4];
    if ((t & 63) == 0) wsum[t >> 6] = v;
    __syncthreads();
    if (t == 0) partial[b] = wsum[0] + wsum[1] + wsum[2] + wsum[3];
}

__global__ void csr_offsets_kernel(const int* __restrict__ deg, const int* __restrict__ partial,
                                   int* __restrict__ row_start, int* __restrict__ cursor) {
    __shared__ int sb[SCAN_NB];
    __shared__ int wsumA[4];
    __shared__ int wsumB[4];
    int t = threadIdx.x, b = blockIdx.x;
    int lane = t & 63, w = t >> 6;
    {   // exclusive scan of partial -> sb
        int v = (t < SCAN_NB) ? partial[t] : 0;
        int incl = v;
        #pragma unroll
        for (int off = 1; off < 64; off <<= 1) {
            int u = __shfl_up(incl, off, 64);
            if (lane >= off) incl += u;
        }
        if (lane == 63) wsumA[w] = incl;
        __syncthreads();
        int woff = 0;
        #pragma unroll
        for (int k = 0; k < 4; ++k) if (k < w) woff += wsumA[k];
        if (t < SCAN_NB) sb[t] = woff + incl - v;
        __syncthreads();
    }
    int i = b * 256 + t;
    int v = (i < N_NODES) ? deg[i] : 0;
    int incl = v;
    #pragma unroll
    for (int off = 1; off < 64; off <<= 1) {
        int u = __shfl_up(incl, off, 64);
        if (lane >= off) incl += u;
    }
    if (lane == 63) wsumB[w] = incl;
    __syncthreads();
    int woff = sb[b];
    #pragma unroll
    for (int k = 0; k < 4; ++k) if (k < w) woff += wsumB[k];
    int excl = woff + incl - v;
    if (i < N_NODES) { row_start[i] = excl; cursor[i] = excl; }
    else if (i == N_NODES) row_start[i] = excl;   // == N_EDGES
}

// scatter: claim slot via cursor atomic (row order = atomic order, same class
// of nondeterminism as the old rank-based order).
__device__ __forceinline__ void scatter_body(int bid, const int* __restrict__ src,
                                             const int* __restrict__ dst,
                                             int* __restrict__ cursor,
                                             int* __restrict__ csr_src) {
    int i = bid * 256 + threadIdx.x;
    if (i >= EDGE_Q) return;
    int e0 = i, e1 = i + EDGE_Q, e2 = i + 2 * EDGE_Q, e3 = i + 3 * EDGE_Q;
    int d0 = dst[e0], d1 = dst[e1], d2 = dst[e2], d3 = dst[e3];
    int s0 = src[e0], s1 = src[e1], s2 = src[e2], s3 = src[e3];
    int p0 = atomicAdd(&cursor[d0], 1);
    int p1 = atomicAdd(&cursor[d1], 1);
    int p2 = atomicAdd(&cursor[d2], 1);
    int p3 = atomicAdd(&cursor[d3], 1);
    csr_src[p0] = s0;
    csr_src[p1] = s1;
    csr_src[p2] = s2;
    csr_src[p3] = s3;
}

// ---------------- node pipeline ----------------

// Pre-pack W into MFMA B-fragment lane order (bf16).
__device__ __forceinline__ void wfrag_body(const float* __restrict__ W,
                                           unsigned* __restrict__ wf, int slot) {
    int f = slot >> 6, l = slot & 63;
    int n = l & 15, q = l >> 4;
    int ct = f >> 2, kq = f & 3;
    int col = 16 * ct + n;
    int k0 = 32 * kq + 8 * q;
    uint4 o;
    o.x = pack_bf2(W[(k0 + 0) * 128 + col], W[(k0 + 1) * 128 + col]);
    o.y = pack_bf2(W[(k0 + 2) * 128 + col], W[(k0 + 3) * 128 + col]);
    o.z = pack_bf2(W[(k0 + 4) * 128 + col], W[(k0 + 5) * 128 + col]);
    o.w = pack_bf2(W[(k0 + 6) * 128 + col], W[(k0 + 7) * 128 + col]);
    ((uint4*)wf)[slot] = o;
}

// prep: both W-frag packs + zero deg + zero pkeys, one launch.
__global__ void prep_kernel(const float* __restrict__ W0, const float* __restrict__ W1,
                            unsigned* __restrict__ wf0, unsigned* __restrict__ wf1,
                            int* __restrict__ deg, unsigned* __restrict__ pkeys) {
    int b = blockIdx.x, t = threadIdx.x;
    if (b < 8) {
        wfrag_body(W0, wf0, b * 256 + t);
    } else if (b < 16) {
        wfrag_body(W1, wf1, (b - 8) * 256 + t);
    } else if (b < 16 + SCAN_NB) {
        int i = (b - 16) * 256 + t;
        if (i < N_NODES) deg[i] = 0;
    } else {
        int i = (b - 16 - SCAN_NB) * 256 + t;
        if (i < N_GRAPHS * 128) pkeys[i] = 0;
    }
}

// feat = h @ W via MFMA 16x16x32 bf16. 64 nodes/block, 4 waves.
// featb NODE-major: featb[node*64 + ct*8 + pair] (bf16 channel pairs).
template<int IN_BF16>
__device__ __forceinline__ void feat_body(int bid, const void* __restrict__ hin,
                                          const int* __restrict__ wid,
                                          const unsigned* __restrict__ wf,
                                          const float* __restrict__ al,
                                          const float* __restrict__ ar,
                                          unsigned* __restrict__ featb,
                                          float* __restrict__ el, float* __restrict__ er) {
    __shared__ unsigned hl[64 * 68];     // 17408 B
    int t = threadIdx.x;
    int n0 = bid * 64;
    if (IN_BF16) {
        const uint4* hb4 = (const uint4*)hin;
        #pragma unroll
        for (int r = 0; r < 4; ++r) {    // 1024 uint4 = 64 nodes x 16
            int i = t + 256 * r;
            int n = i >> 4, q = i & 15;
            uint4 v = {0u, 0u, 0u, 0u};
            int gn = n0 + n;
            if (gn < N_NODES) v = hb4[(size_t)gn * 16 + q];
            *(uint4*)&hl[n * 68 + q * 4] = v;
        }
    } else {
        const float4* h4 = (const float4*)hin;
        #pragma unroll
        for (int r = 0; r < 8; ++r) {    // 2048 float4 = 64 nodes x 32
            int i = t + 256 * r;
            int n = i >> 5, q4 = i & 31;
            float4 v = {0.f, 0.f, 0.f, 0.f};
            int gn = n0 + n;
            if (gn < N_NODES) {
                int row = wid ? wid[gn] : gn;
                v = h4[(size_t)row * 32 + q4];
            }
            hl[n * 68 + q4 * 2]     = pack_bf2(v.x, v.y);
            hl[n * 68 + q4 * 2 + 1] = pack_bf2(v.z, v.w);
        }
    }
    __syncthreads();
    int w = t >> 6, lane = t & 63;
    int col = lane & 15, quad = lane >> 4;
    int nbase = n0 + 16 * w;
    bf16x8 afr[4];
    #pragma unroll
    for (int kq = 0; kq < 4; ++kq)
        afr[kq] = *(const bf16x8*)&hl[(16 * w + col) * 68 + 16 * kq + 4 * quad];
    f32x4 acc[8];
    #pragma unroll
    for (int ct = 0; ct < 8; ++ct) acc[ct] = (f32x4){0.f, 0.f, 0.f, 0.f};
    const uint4* wf4 = (const uint4*)wf;
    #pragma unroll
    for (int ct = 0; ct < 8; ++ct) {
        #pragma unroll
        for (int kq = 0; kq < 4; ++kq) {
            uint4 braw = wf4[(ct * 4 + kq) * 64 + lane];
            bf16x8 bfr = *(const bf16x8*)&braw;
            acc[ct] = __builtin_amdgcn_mfma_f32_16x16x32_bf16(afr[kq], bfr, acc[ct], 0, 0, 0);
        }
    }
    #pragma unroll
    for (int ct = 0; ct < 8; ++ct) {
        #pragma unroll
        for (int reg = 0; reg < 4; ++reg) {
            float v = acc[ct][reg];
            float pv = __shfl_xor(v, 1, 64);
            int node = nbase + quad * 4 + reg;
            if (!(col & 1) && node < N_NODES)
                featb[(size_t)node * 64 + ct * 8 + (col >> 1)] = pack_bf2(v, pv);
        }
    }
    float alv[8], arv[8];
    #pragma unroll
    for (int ct = 0; ct < 8; ++ct) {
        alv[ct] = al[ct * 16 + col];
        arv[ct] = ar[ct * 16 + col];
    }
    #pragma unroll
    for (int reg = 0; reg < 4; ++reg) {
        int node = nbase + quad * 4 + reg;
        #pragma unroll
        for (int hd = 0; hd < 4; ++hd) {
            float pl = acc[2 * hd][reg] * alv[2 * hd] + acc[2 * hd + 1][reg] * alv[2 * hd + 1];
            float pr = acc[2 * hd][reg] * arv[2 * hd] + acc[2 * hd + 1][reg] * arv[2 * hd + 1];
            #pragma unroll
            for (int off = 1; off < 16; off <<= 1) {
                pl += __shfl_xor(pl, off, 64);
                pr += __shfl_xor(pr, off, 64);
            }
            if (col == hd && node < N_NODES) {
                el[node * 4 + hd] = pl * LOG2E;
                er[node * 4 + hd] = pr * LOG2E;
            }
        }
    }
}

template<int IN_BF16>
__global__ __launch_bounds__(256)
void feat_kernel_t(const void* __restrict__ hin, const int* __restrict__ wid,
                   const unsigned* __restrict__ wf,
                   const float* __restrict__ al, const float* __restrict__ ar,
                   unsigned* __restrict__ featb, float* __restrict__ el,
                   float* __restrict__ er) {
    feat_body<IN_BF16>(blockIdx.x, hin, wid, wf, al, ar, featb, el, er);
}

// scatter (CSR finalize) fused with layer-0 feat (independent work)
__global__ __launch_bounds__(256)
void scatter_feat0_kernel(const int* __restrict__ src, const int* __restrict__ dst,
                          int* __restrict__ cursor, int* __restrict__ csr_src,
                          const float* __restrict__ emb, const int* __restrict__ wid,
                          const unsigned* __restrict__ wf0,
                          const float* __restrict__ al0, const float* __restrict__ ar0,
                          unsigned* __restrict__ featb, float* __restrict__ el,
                          float* __restrict__ er) {
    if (blockIdx.x < EDGE_NB) {
        scatter_body(blockIdx.x, src, dst, cursor, csr_src);
    } else {
        feat_body<0>(blockIdx.x - EDGE_NB, emb, wid, wf0, al0, ar0, featb, el, er);
    }
}

// Fused softmax + aggregation + ELU. One 64-lane wave per dst node.
// 16 lanes per edge, 4 edges per wave-iter (8 with unroll).
template<int OUT_BF16>
__global__ void gat_aggregate_t(const int* __restrict__ row_start, const int* __restrict__ csr_src,
                                const unsigned* __restrict__ featb, const float* __restrict__ el,
                                const float* __restrict__ er, float* __restrict__ houtf,
                                unsigned* __restrict__ houtb) {
    int lane = threadIdx.x & 63;
    int d = blockIdx.x * 4 + (threadIdx.x >> 6);
    int beg = row_start[d], end = row_start[d + 1];
    int eg = lane >> 4;          // edge slot 0..3
    int li = lane & 15;          // channel group: channels [8li, 8li+8)
    int hc = li >> 2;            // head of these channels
    float er_h = er[d * 4 + hc];
    float a0 = 0.f, a1 = 0.f, a2 = 0.f, a3 = 0.f;
    float a4 = 0.f, a5 = 0.f, a6 = 0.f, a7 = 0.f;
    float dsum = 0.f;
    int b8 = beg + ((end - beg) & ~7);
    for (int base = beg; base < b8; base += 8) {
        int ea = base + eg, eb = base + 4 + eg;
        int sa = csr_src[ea];
        int sb = csr_src[eb];
        float la = el[sa * 4 + hc];
        float lb = el[sb * 4 + hc];
        uint4 pa = *(const uint4*)(featb + (size_t)sa * 64 + li * 4);
        uint4 pb = *(const uint4*)(featb + (size_t)sb * 64 + li * 4);
        float va = la + er_h; va = fmaxf(va, NEG_SLOPE * va);
        float vb = lb + er_h; vb = fmaxf(vb, NEG_SLOPE * vb);
        float xa = exp2f(va), xb = exp2f(vb);
        dsum += xa + xb;
        a0 += __uint_as_float(pa.x << 16) * xa;
        a1 += __uint_as_float(pa.x & 0xFFFF0000u) * xa;
        a2 += __uint_as_float(pa.y << 16) * xa;
        a3 += __uint_as_float(pa.y & 0xFFFF0000u) * xa;
        a4 += __uint_as_float(pa.z << 16) * xa;
        a5 += __uint_as_float(pa.z & 0xFFFF0000u) * xa;
        a6 += __uint_as_float(pa.w << 16) * xa;
        a7 += __uint_as_float(pa.w & 0xFFFF0000u) * xa;
        a0 += __uint_as_float(pb.x << 16) * xb;
        a1 += __uint_as_float(pb.x & 0xFFFF0000u) * xb;
        a2 += __uint_as_float(pb.y << 16) * xb;
        a3 += __uint_as_float(pb.y & 0xFFFF0000u) * xb;
        a4 += __uint_as_float(pb.z << 16) * xb;
        a5 += __uint_as_float(pb.z & 0xFFFF0000u) * xb;
        a6 += __uint_as_float(pb.w << 16) * xb;
        a7 += __uint_as_float(pb.w & 0xFFFF0000u) * xb;
    }
    for (int ee = b8 + eg; ee < end; ee += 4) {
        int s = csr_src[ee];
        float lv = el[s * 4 + hc];
        uint4 pv = *(const uint4*)(featb + (size_t)s * 64 + li * 4);
        float v = lv + er_h; v = fmaxf(v, NEG_SLOPE * v);
        float x = exp2f(v);
        dsum += x;
        a0 += __uint_as_float(pv.x << 16) * x;
        a1 += __uint_as_float(pv.x & 0xFFFF0000u) * x;
        a2 += __uint_as_float(pv.y << 16) * x;
        a3 += __uint_as_float(pv.y & 0xFFFF0000u) * x;
        a4 += __uint_as_float(pv.z << 16) * x;
        a5 += __uint_as_float(pv.z & 0xFFFF0000u) * x;
        a6 += __uint_as_float(pv.w << 16) * x;
        a7 += __uint_as_float(pv.w & 0xFFFF0000u) * x;
    }
    #pragma unroll
    for (int off = 16; off < 64; off <<= 1) {
        a0 += __shfl_xor(a0, off, 64);
        a1 += __shfl_xor(a1, off, 64);
        a2 += __shfl_xor(a2, off, 64);
        a3 += __shfl_xor(a3, off, 64);
        a4 += __shfl_xor(a4, off, 64);
        a5 += __shfl_xor(a5, off, 64);
        a6 += __shfl_xor(a6, off, 64);
        a7 += __shfl_xor(a7, off, 64);
        dsum += __shfl_xor(dsum, off, 64);
    }
    if (eg == 0) {
        float inv = 1.f / (dsum + 1e-10f);
        float o0 = elu_fast(a0 * inv), o1 = elu_fast(a1 * inv);
        float o2 = elu_fast(a2 * inv), o3 = elu_fast(a3 * inv);
        float o4 = elu_fast(a4 * inv), o5 = elu_fast(a5 * inv);
        float o6 = elu_fast(a6 * inv), o7 = elu_fast(a7 * inv);
        if (OUT_BF16) {
            uint4 wv;
            wv.x = pack_bf2(o0, o1);
            wv.y = pack_bf2(o2, o3);
            wv.z = pack_bf2(o4, o5);
            wv.w = pack_bf2(o6, o7);
            ((uint4*)(houtb + (size_t)d * 64))[li] = wv;
        } else {
            float4* op = (float4*)(houtf + (size_t)d * 128);
            float4 w0 = {o0, o1, o2, o3};
            float4 w1 = {o4, o5, o6, o7};
            op[li * 2] = w0;
            op[li * 2 + 1] = w1;
        }
    }
}

// ---------------- pooling / loss ----------------

__global__ void pool_kernel(const int* __restrict__ gid, const float* __restrict__ h,
                            unsigned* __restrict__ pkeys) {
    int t = threadIdx.x;
    int c = t & 127;
    int par = t >> 7;              // 0/1
    int n0 = blockIdx.x * POOL_CHUNK;
    float m = 0.f;
    int cur_g = -1;
    for (int n = n0 + par; n < n0 + POOL_CHUNK; n += 2) {
        int g = gid[n];
        if (g != cur_g) {
            if (cur_g >= 0) atomicMax(&pkeys[cur_g * 128 + c], fkey(m));
            cur_g = g;
            m = -3.0e38f;
        }
        m = fmaxf(m, h[(size_t)n * 128 + c]);
    }
    if (cur_g >= 0) atomicMax(&pkeys[cur_g * 128 + c], fkey(m));
}

// logits + loss fused: one block, 4 waves.
__global__ void logits_final_kernel(const unsigned* __restrict__ pkeys,
                                    const float* __restrict__ w, const float* __restrict__ bptr,
                                    const float* __restrict__ y, float* __restrict__ out) {
    __shared__ float slog[N_GRAPHS];
    int t = threadIdx.x;
    int wv = t >> 6, lane = t & 63;
    float b = bptr[0];
    #pragma unroll
    for (int k = 0; k < 16; ++k) {
        int g = wv * 16 + k;
        float sum = 0.f;
        #pragma unroll
        for (int c0 = 0; c0 < 128; c0 += 64) {
            int c = c0 + lane;
            unsigned kk = pkeys[g * 128 + c];
            float v = (kk == 0u) ? 0.f : kval(kk);
            sum += v * w[c];
        }
        #pragma unroll
        for (int off = 32; off; off >>= 1) sum += __shfl_down(sum, off, 64);
        if (lane == 0) slog[g] = sum + b;
    }
    __syncthreads();
    if (t < N_GRAPHS) {
        float l = slog[t];
        float term = fmaxf(l, 0.f) - l * y[t] + log1pf(expf(-fabsf(l)));
        float s = term;
        #pragma unroll
        for (int off = 32; off; off >>= 1) s += __shfl_down(s, off, 64);
        out[1 + t] = 1.f / (1.f + expf(-l));
        if (t == 0) out[0] = s * (1.f / 64.f);
    }
}

extern "C" void kernel_launch(void* const* d_in, const int* in_sizes, int n_in,
                              void* d_out, int out_size, void* d_ws, size_t ws_size,
                              hipStream_t stream) {
    const int* word_ids  = (const int*)d_in[0];
    const int* esrc      = (const int*)d_in[1];
    const int* edst      = (const int*)d_in[2];
    const int* gid       = (const int*)d_in[3];
    const float* y_data  = (const float*)d_in[4];
    const float* emb     = (const float*)d_in[5];
    const float* W0      = (const float*)d_in[6];
    const float* al0     = (const float*)d_in[7];
    const float* ar0     = (const float*)d_in[8];
    const float* W1      = (const float*)d_in[9];
    const float* al1     = (const float*)d_in[10];
    const float* ar1     = (const float*)d_in[11];
    const float* out_w   = (const float*)d_in[12];
    const float* out_b   = (const float*)d_in[13];
    float* out = (float*)d_out;

    // workspace layout (float offsets)
    float* ws = (float*)d_ws;
    unsigned* featb  = (unsigned*)ws;                // N*64 uints = 3,200,000
    unsigned* hb     = (unsigned*)(ws + 3200000);    // N*64 uints (bf16 layer0 out)
    float*    hout   = ws + 6400000;                 // N*128 f32 (layer1 out)
    float*    el     = ws + 12800000;                // 200,000
    float*    er     = ws + 13000000;                // 200,000
    int*      row_st = (int*)(ws + 13200000);        // 50,001 (pad to 50,004)
    int*      deg    = (int*)(ws + 13250004);        // 50,000
    int*      cursor = (int*)(ws + 13300004);        // 50,004
    int*      csrsrc = (int*)(ws + 13350008);        // 800,000
    int*      partial= (int*)(ws + 14150008);        // 196 (pad to 200)
    unsigned* pkeys  = (unsigned*)(ws + 14150208);   // 8,192
    unsigned* wf0    = (unsigned*)(ws + 14158400);   // 8,192 uints (16B-aligned)
    unsigned* wf1    = (unsigned*)(ws + 14166592);   // 8,192 uints

    // prep (W-frags, deg/pkeys zero) then CSR counting
    prep_kernel<<<16 + SCAN_NB + 32, 256, 0, stream>>>(W0, W1, wf0, wf1, deg, pkeys);
    hist_kernel<<<EDGE_NB, 256, 0, stream>>>(edst, deg);
    partial_kernel<<<SCAN_NB, 256, 0, stream>>>(deg, partial);
    csr_offsets_kernel<<<SCAN_NB, 256, 0, stream>>>(deg, partial, row_st, cursor);

    // CSR scatter (cursor-claim) fused with layer-0 feat (independent work)
    scatter_feat0_kernel<<<EDGE_NB + FEAT_NB, 256, 0, stream>>>(
        esrc, edst, cursor, csrsrc, emb, word_ids, wf0, al0, ar0, featb, el, er);

    // layer 0 aggregate -> packed bf16 node features; layer 1
    gat_aggregate_t<1><<<12500, 256, 0, stream>>>(row_st, csrsrc, featb, el, er, nullptr, hb);
    feat_kernel_t<1><<<FEAT_NB, 256, 0, stream>>>(hb, nullptr, wf1, al1, ar1, featb, el, er);
    gat_aggregate_t<0><<<12500, 256, 0, stream>>>(row_st, csrsrc, featb, el, er, hout, nullptr);

    pool_kernel<<<POOL_NB, 256, 0, stream>>>(gid, hout, pkeys);
    logits_final_kernel<<<1, 256, 0, stream>>>(pkeys, out_w, out_b, y_data, out);
}

// Round 7
// 270.390 us; speedup vs baseline: 1.4709x; 1.1514x over previous
//
#include <hip/hip_runtime.h>
#include <math.h>

#define N_NODES 50000
#define N_EDGES 800000
#define HEADS 4
#define N_GRAPHS 64
#define NEG_SLOPE 0.2f
#define LOG2E 1.4426950408889634f
#define SCAN_NB 196            // 196*256 = 50176 >= N_NODES
#define POOL_CHUNK 50
#define POOL_NB 1000           // 1000*50 = 50000 exactly
#define FEAT_NB 782            // ceil(50000/64)
#define EDGE_Q 200000          // N_EDGES/4: 4 edges per thread
#define EDGE_NB 782            // ceil(200000/256)

typedef __attribute__((ext_vector_type(8))) short bf16x8;
typedef __attribute__((ext_vector_type(4))) float f32x4;

// monotone float<->uint key for atomicMax-based segment max (pooling).
__device__ __forceinline__ unsigned fkey(float f) {
    unsigned u = __float_as_uint(f);
    return (u & 0x80000000u) ? ~u : (u | 0x80000000u);
}
__device__ __forceinline__ float kval(unsigned k) {
    unsigned u = (k & 0x80000000u) ? (k & 0x7FFFFFFFu) : ~k;
    return __uint_as_float(u);
}

// f32 -> bf16 (RNE), two packed into one uint (lo = first channel)
__device__ __forceinline__ unsigned short f2bf(float f) {
    unsigned u = __float_as_uint(f);
    u += 0x7FFFu + ((u >> 16) & 1u);
    return (unsigned short)(u >> 16);
}
__device__ __forceinline__ unsigned pack_bf2(float a, float b) {
    return (unsigned)f2bf(a) | ((unsigned)f2bf(b) << 16);
}

// cheap ELU: o>0 ? o : exp(o)-1 via exp2 (saves ~10 inst vs expm1f; abs err ~1e-8)
__device__ __forceinline__ float elu_fast(float o) {
    float e = exp2f(o * LOG2E) - 1.f;
    return o > 0.f ? o : e;
}

// ---------------- CSR build (counting sort by dst, rank-based) ----------------

__global__ void hist_kernel(const int* __restrict__ dst, int* __restrict__ deg,
                            int* __restrict__ rank) {
    int i = blockIdx.x * 256 + threadIdx.x;
    if (i >= EDGE_Q) return;
    int e0 = i, e1 = i + EDGE_Q, e2 = i + 2 * EDGE_Q, e3 = i + 3 * EDGE_Q;
    int d0 = dst[e0], d1 = dst[e1], d2 = dst[e2], d3 = dst[e3];
    int r0 = atomicAdd(&deg[d0], 1);
    int r1 = atomicAdd(&deg[d1], 1);
    int r2 = atomicAdd(&deg[d2], 1);
    int r3 = atomicAdd(&deg[d3], 1);
    rank[e0] = r0; rank[e1] = r1; rank[e2] = r2; rank[e3] = r3;
}

__global__ void partial_kernel(const int* __restrict__ deg, int* __restrict__ partial) {
    int t = threadIdx.x, b = blockIdx.x;
    int i = b * 256 + t;
    int v = (i < N_NODES) ? deg[i] : 0;
    #pragma unroll
    for (int off = 1; off < 64; off <<= 1) v += __shfl_xor(v, off, 64);
    __shared__ int wsum[4];
    if ((t & 63) == 0) wsum[t >> 6] = v;
    __syncthreads();
    if (t == 0) partial[b] = wsum[0] + wsum[1] + wsum[2] + wsum[3];
}

__global__ void csr_offsets_kernel(const int* __restrict__ deg, const int* __restrict__ partial,
                                   int* __restrict__ row_start) {
    __shared__ int sb[SCAN_NB];
    __shared__ int wsumA[4];
    __shared__ int wsumB[4];
    int t = threadIdx.x, b = blockIdx.x;
    int lane = t & 63, w = t >> 6;
    {   // exclusive scan of partial -> sb
        int v = (t < SCAN_NB) ? partial[t] : 0;
        int incl = v;
        #pragma unroll
        for (int off = 1; off < 64; off <<= 1) {
            int u = __shfl_up(incl, off, 64);
            if (lane >= off) incl += u;
        }
        if (lane == 63) wsumA[w] = incl;
        __syncthreads();
        int woff = 0;
        #pragma unroll
        for (int k = 0; k < 4; ++k) if (k < w) woff += wsumA[k];
        if (t < SCAN_NB) sb[t] = woff + incl - v;
        __syncthreads();
    }
    int i = b * 256 + t;
    int v = (i < N_NODES) ? deg[i] : 0;
    int incl = v;
    #pragma unroll
    for (int off = 1; off < 64; off <<= 1) {
        int u = __shfl_up(incl, off, 64);
        if (lane >= off) incl += u;
    }
    if (lane == 63) wsumB[w] = incl;
    __syncthreads();
    int woff = sb[b];
    #pragma unroll
    for (int k = 0; k < 4; ++k) if (k < w) woff += wsumB[k];
    int excl = woff + incl - v;
    if (i < N_NODES) row_start[i] = excl;
    else if (i == N_NODES) row_start[i] = excl;   // == N_EDGES
}

__device__ __forceinline__ void scatter_body(int bid, const int* __restrict__ src,
                                             const int* __restrict__ dst,
                                             const int* __restrict__ rank,
                                             const int* __restrict__ row_start,
                                             int* __restrict__ csr_src) {
    int i = bid * 256 + threadIdx.x;
    if (i >= EDGE_Q) return;
    int e0 = i, e1 = i + EDGE_Q, e2 = i + 2 * EDGE_Q, e3 = i + 3 * EDGE_Q;
    int d0 = dst[e0], d1 = dst[e1], d2 = dst[e2], d3 = dst[e3];
    int k0 = rank[e0], k1 = rank[e1], k2 = rank[e2], k3 = rank[e3];
    int s0 = src[e0], s1 = src[e1], s2 = src[e2], s3 = src[e3];
    csr_src[row_start[d0] + k0] = s0;
    csr_src[row_start[d1] + k1] = s1;
    csr_src[row_start[d2] + k2] = s2;
    csr_src[row_start[d3] + k3] = s3;
}

// ---------------- node pipeline ----------------

// Pre-pack W into MFMA B-fragment lane order (bf16).
__device__ __forceinline__ void wfrag_body(const float* __restrict__ W,
                                           unsigned* __restrict__ wf, int slot) {
    int f = slot >> 6, l = slot & 63;
    int n = l & 15, q = l >> 4;
    int ct = f >> 2, kq = f & 3;
    int col = 16 * ct + n;
    int k0 = 32 * kq + 8 * q;
    uint4 o;
    o.x = pack_bf2(W[(k0 + 0) * 128 + col], W[(k0 + 1) * 128 + col]);
    o.y = pack_bf2(W[(k0 + 2) * 128 + col], W[(k0 + 3) * 128 + col]);
    o.z = pack_bf2(W[(k0 + 4) * 128 + col], W[(k0 + 5) * 128 + col]);
    o.w = pack_bf2(W[(k0 + 6) * 128 + col], W[(k0 + 7) * 128 + col]);
    ((uint4*)wf)[slot] = o;
}

// prep: both W-frag packs + zero deg + zero pkeys, one launch.
__global__ void prep_kernel(const float* __restrict__ W0, const float* __restrict__ W1,
                            unsigned* __restrict__ wf0, unsigned* __restrict__ wf1,
                            int* __restrict__ deg, unsigned* __restrict__ pkeys) {
    int b = blockIdx.x, t = threadIdx.x;
    if (b < 8) {
        wfrag_body(W0, wf0, b * 256 + t);
    } else if (b < 16) {
        wfrag_body(W1, wf1, (b - 8) * 256 + t);
    } else if (b < 16 + SCAN_NB) {
        int i = (b - 16) * 256 + t;
        if (i < N_NODES) deg[i] = 0;
    } else {
        int i = (b - 16 - SCAN_NB) * 256 + t;
        if (i < N_GRAPHS * 128) pkeys[i] = 0;
    }
}

// feat = h @ W via MFMA 16x16x32 bf16. 64 nodes/block, 4 waves.
// featb NODE-major: featb[node*64 + ct*8 + pair] (bf16 channel pairs).
template<int IN_BF16>
__device__ __forceinline__ void feat_body(int bid, const void* __restrict__ hin,
                                          const int* __restrict__ wid,
                                          const unsigned* __restrict__ wf,
                                          const float* __restrict__ al,
                                          const float* __restrict__ ar,
                                          unsigned* __restrict__ featb,
                                          float* __restrict__ el, float* __restrict__ er) {
    __shared__ unsigned hl[64 * 68];     // 17408 B
    int t = threadIdx.x;
    int n0 = bid * 64;
    if (IN_BF16) {
        const uint4* hb4 = (const uint4*)hin;
        #pragma unroll
        for (int r = 0; r < 4; ++r) {    // 1024 uint4 = 64 nodes x 16
            int i = t + 256 * r;
            int n = i >> 4, q = i & 15;
            uint4 v = {0u, 0u, 0u, 0u};
            int gn = n0 + n;
            if (gn < N_NODES) v = hb4[(size_t)gn * 16 + q];
            *(uint4*)&hl[n * 68 + q * 4] = v;
        }
    } else {
        const float4* h4 = (const float4*)hin;
        #pragma unroll
        for (int r = 0; r < 8; ++r) {    // 2048 float4 = 64 nodes x 32
            int i = t + 256 * r;
            int n = i >> 5, q4 = i & 31;
            float4 v = {0.f, 0.f, 0.f, 0.f};
            int gn = n0 + n;
            if (gn < N_NODES) {
                int row = wid ? wid[gn] : gn;
                v = h4[(size_t)row * 32 + q4];
            }
            hl[n * 68 + q4 * 2]     = pack_bf2(v.x, v.y);
            hl[n * 68 + q4 * 2 + 1] = pack_bf2(v.z, v.w);
        }
    }
    __syncthreads();
    int w = t >> 6, lane = t & 63;
    int col = lane & 15, quad = lane >> 4;
    int nbase = n0 + 16 * w;
    bf16x8 afr[4];
    #pragma unroll
    for (int kq = 0; kq < 4; ++kq)
        afr[kq] = *(const bf16x8*)&hl[(16 * w + col) * 68 + 16 * kq + 4 * quad];
    f32x4 acc[8];
    #pragma unroll
    for (int ct = 0; ct < 8; ++ct) acc[ct] = (f32x4){0.f, 0.f, 0.f, 0.f};
    const uint4* wf4 = (const uint4*)wf;
    #pragma unroll
    for (int ct = 0; ct < 8; ++ct) {
        #pragma unroll
        for (int kq = 0; kq < 4; ++kq) {
            uint4 braw = wf4[(ct * 4 + kq) * 64 + lane];
            bf16x8 bfr = *(const bf16x8*)&braw;
            acc[ct] = __builtin_amdgcn_mfma_f32_16x16x32_bf16(afr[kq], bfr, acc[ct], 0, 0, 0);
        }
    }
    #pragma unroll
    for (int ct = 0; ct < 8; ++ct) {
        #pragma unroll
        for (int reg = 0; reg < 4; ++reg) {
            float v = acc[ct][reg];
            float pv = __shfl_xor(v, 1, 64);
            int node = nbase + quad * 4 + reg;
            if (!(col & 1) && node < N_NODES)
                featb[(size_t)node * 64 + ct * 8 + (col >> 1)] = pack_bf2(v, pv);
        }
    }
    float alv[8], arv[8];
    #pragma unroll
    for (int ct = 0; ct < 8; ++ct) {
        alv[ct] = al[ct * 16 + col];
        arv[ct] = ar[ct * 16 + col];
    }
    #pragma unroll
    for (int reg = 0; reg < 4; ++reg) {
        int node = nbase + quad * 4 + reg;
        #pragma unroll
        for (int hd = 0; hd < 4; ++hd) {
            float pl = acc[2 * hd][reg] * alv[2 * hd] + acc[2 * hd + 1][reg] * alv[2 * hd + 1];
            float pr = acc[2 * hd][reg] * arv[2 * hd] + acc[2 * hd + 1][reg] * arv[2 * hd + 1];
            #pragma unroll
            for (int off = 1; off < 16; off <<= 1) {
                pl += __shfl_xor(pl, off, 64);
                pr += __shfl_xor(pr, off, 64);
            }
            if (col == hd && node < N_NODES) {
                el[node * 4 + hd] = pl * LOG2E;
                er[node * 4 + hd] = pr * LOG2E;
            }
        }
    }
}

template<int IN_BF16>
__global__ __launch_bounds__(256)
void feat_kernel_t(const void* __restrict__ hin, const int* __restrict__ wid,
                   const unsigned* __restrict__ wf,
                   const float* __restrict__ al, const float* __restrict__ ar,
                   unsigned* __restrict__ featb, float* __restrict__ el,
                   float* __restrict__ er) {
    feat_body<IN_BF16>(blockIdx.x, hin, wid, wf, al, ar, featb, el, er);
}

// scatter (CSR finalize) fused with layer-0 feat (independent work)
__global__ __launch_bounds__(256)
void scatter_feat0_kernel(const int* __restrict__ src, const int* __restrict__ dst,
                          const int* __restrict__ rank, const int* __restrict__ row_start,
                          int* __restrict__ csr_src,
                          const float* __restrict__ emb, const int* __restrict__ wid,
                          const unsigned* __restrict__ wf0,
                          const float* __restrict__ al0, const float* __restrict__ ar0,
                          unsigned* __restrict__ featb, float* __restrict__ el,
                          float* __restrict__ er) {
    if (blockIdx.x < EDGE_NB) {
        scatter_body(blockIdx.x, src, dst, rank, row_start, csr_src);
    } else {
        feat_body<0>(blockIdx.x - EDGE_NB, emb, wid, wf0, al0, ar0, featb, el, er);
    }
}

// Fused softmax + aggregation + ELU. One 64-lane wave per dst node.
// 16 lanes per edge, 4 edges per wave-iter (8 with unroll).
template<int OUT_BF16>
__global__ void gat_aggregate_t(const int* __restrict__ row_start, const int* __restrict__ csr_src,
                                const unsigned* __restrict__ featb, const float* __restrict__ el,
                                const float* __restrict__ er, float* __restrict__ houtf,
                                unsigned* __restrict__ houtb) {
    int lane = threadIdx.x & 63;
    int d = blockIdx.x * 4 + (threadIdx.x >> 6);
    int beg = row_start[d], end = row_start[d + 1];
    int eg = lane >> 4;          // edge slot 0..3
    int li = lane & 15;          // channel group: channels [8li, 8li+8)
    int hc = li >> 2;            // head of these channels
    float er_h = er[d * 4 + hc];
    float a0 = 0.f, a1 = 0.f, a2 = 0.f, a3 = 0.f;
    float a4 = 0.f, a5 = 0.f, a6 = 0.f, a7 = 0.f;
    float dsum = 0.f;
    int b8 = beg + ((end - beg) & ~7);
    for (int base = beg; base < b8; base += 8) {
        int ea = base + eg, eb = base + 4 + eg;
        int sa = csr_src[ea];
        int sb = csr_src[eb];
        float la = el[sa * 4 + hc];
        float lb = el[sb * 4 + hc];
        uint4 pa = *(const uint4*)(featb + (size_t)sa * 64 + li * 4);
        uint4 pb = *(const uint4*)(featb + (size_t)sb * 64 + li * 4);
        float va = la + er_h; va = fmaxf(va, NEG_SLOPE * va);
        float vb = lb + er_h; vb = fmaxf(vb, NEG_SLOPE * vb);
        float xa = exp2f(va), xb = exp2f(vb);
        dsum += xa + xb;
        a0 += __uint_as_float(pa.x << 16) * xa;
        a1 += __uint_as_float(pa.x & 0xFFFF0000u) * xa;
        a2 += __uint_as_float(pa.y << 16) * xa;
        a3 += __uint_as_float(pa.y & 0xFFFF0000u) * xa;
        a4 += __uint_as_float(pa.z << 16) * xa;
        a5 += __uint_as_float(pa.z & 0xFFFF0000u) * xa;
        a6 += __uint_as_float(pa.w << 16) * xa;
        a7 += __uint_as_float(pa.w & 0xFFFF0000u) * xa;
        a0 += __uint_as_float(pb.x << 16) * xb;
        a1 += __uint_as_float(pb.x & 0xFFFF0000u) * xb;
        a2 += __uint_as_float(pb.y << 16) * xb;
        a3 += __uint_as_float(pb.y & 0xFFFF0000u) * xb;
        a4 += __uint_as_float(pb.z << 16) * xb;
        a5 += __uint_as_float(pb.z & 0xFFFF0000u) * xb;
        a6 += __uint_as_float(pb.w << 16) * xb;
        a7 += __uint_as_float(pb.w & 0xFFFF0000u) * xb;
    }
    for (int ee = b8 + eg; ee < end; ee += 4) {
        int s = csr_src[ee];
        float lv = el[s * 4 + hc];
        uint4 pv = *(const uint4*)(featb + (size_t)s * 64 + li * 4);
        float v = lv + er_h; v = fmaxf(v, NEG_SLOPE * v);
        float x = exp2f(v);
        dsum += x;
        a0 += __uint_as_float(pv.x << 16) * x;
        a1 += __uint_as_float(pv.x & 0xFFFF0000u) * x;
        a2 += __uint_as_float(pv.y << 16) * x;
        a3 += __uint_as_float(pv.y & 0xFFFF0000u) * x;
        a4 += __uint_as_float(pv.z << 16) * x;
        a5 += __uint_as_float(pv.z & 0xFFFF0000u) * x;
        a6 += __uint_as_float(pv.w << 16) * x;
        a7 += __uint_as_float(pv.w & 0xFFFF0000u) * x;
    }
    #pragma unroll
    for (int off = 16; off < 64; off <<= 1) {
        a0 += __shfl_xor(a0, off, 64);
        a1 += __shfl_xor(a1, off, 64);
        a2 += __shfl_xor(a2, off, 64);
        a3 += __shfl_xor(a3, off, 64);
        a4 += __shfl_xor(a4, off, 64);
        a5 += __shfl_xor(a5, off, 64);
        a6 += __shfl_xor(a6, off, 64);
        a7 += __shfl_xor(a7, off, 64);
        dsum += __shfl_xor(dsum, off, 64);
    }
    if (eg == 0) {
        float inv = 1.f / (dsum + 1e-10f);
        float o0 = elu_fast(a0 * inv), o1 = elu_fast(a1 * inv);
        float o2 = elu_fast(a2 * inv), o3 = elu_fast(a3 * inv);
        float o4 = elu_fast(a4 * inv), o5 = elu_fast(a5 * inv);
        float o6 = elu_fast(a6 * inv), o7 = elu_fast(a7 * inv);
        if (OUT_BF16) {
            uint4 wv;
            wv.x = pack_bf2(o0, o1);
            wv.y = pack_bf2(o2, o3);
            wv.z = pack_bf2(o4, o5);
            wv.w = pack_bf2(o6, o7);
            ((uint4*)(houtb + (size_t)d * 64))[li] = wv;
        } else {
            float4* op = (float4*)(houtf + (size_t)d * 128);
            float4 w0 = {o0, o1, o2, o3};
            float4 w1 = {o4, o5, o6, o7};
            op[li * 2] = w0;
            op[li * 2 + 1] = w1;
        }
    }
}

// ---------------- pooling / loss ----------------

__global__ void pool_kernel(const int* __restrict__ gid, const float* __restrict__ h,
                            unsigned* __restrict__ pkeys) {
    int t = threadIdx.x;
    int c = t & 127;
    int par = t >> 7;              // 0/1
    int n0 = blockIdx.x * POOL_CHUNK;
    float m = 0.f;
    int cur_g = -1;
    for (int n = n0 + par; n < n0 + POOL_CHUNK; n += 2) {
        int g = gid[n];
        if (g != cur_g) {
            if (cur_g >= 0) atomicMax(&pkeys[cur_g * 128 + c], fkey(m));
            cur_g = g;
            m = -3.0e38f;
        }
        m = fmaxf(m, h[(size_t)n * 128 + c]);
    }
    if (cur_g >= 0) atomicMax(&pkeys[cur_g * 128 + c], fkey(m));
}

// logits + loss fused: one block, 4 waves.
__global__ void logits_final_kernel(const unsigned* __restrict__ pkeys,
                                    const float* __restrict__ w, const float* __restrict__ bptr,
                                    const float* __restrict__ y, float* __restrict__ out) {
    __shared__ float slog[N_GRAPHS];
    int t = threadIdx.x;
    int wv = t >> 6, lane = t & 63;
    float b = bptr[0];
    #pragma unroll
    for (int k = 0; k < 16; ++k) {
        int g = wv * 16 + k;
        float sum = 0.f;
        #pragma unroll
        for (int c0 = 0; c0 < 128; c0 += 64) {
            int c = c0 + lane;
            unsigned kk = pkeys[g * 128 + c];
            float v = (kk == 0u) ? 0.f : kval(kk);
            sum += v * w[c];
        }
        #pragma unroll
        for (int off = 32; off; off >>= 1) sum += __shfl_down(sum, off, 64);
        if (lane == 0) slog[g] = sum + b;
    }
    __syncthreads();
    if (t < N_GRAPHS) {
        float l = slog[t];
        float term = fmaxf(l, 0.f) - l * y[t] + log1pf(expf(-fabsf(l)));
        float s = term;
        #pragma unroll
        for (int off = 32; off; off >>= 1) s += __shfl_down(s, off, 64);
        out[1 + t] = 1.f / (1.f + expf(-l));
        if (t == 0) out[0] = s * (1.f / 64.f);
    }
}

extern "C" void kernel_launch(void* const* d_in, const int* in_sizes, int n_in,
                              void* d_out, int out_size, void* d_ws, size_t ws_size,
                              hipStream_t stream) {
    const int* word_ids  = (const int*)d_in[0];
    const int* esrc      = (const int*)d_in[1];
    const int* edst      = (const int*)d_in[2];
    const int* gid       = (const int*)d_in[3];
    const float* y_data  = (const float*)d_in[4];
    const float* emb     = (const float*)d_in[5];
    const float* W0      = (const float*)d_in[6];
    const float* al0     = (const float*)d_in[7];
    const float* ar0     = (const float*)d_in[8];
    const float* W1      = (const float*)d_in[9];
    const float* al1     = (const float*)d_in[10];
    const float* ar1     = (const float*)d_in[11];
    const float* out_w   = (const float*)d_in[12];
    const float* out_b   = (const float*)d_in[13];
    float* out = (float*)d_out;

    // workspace layout (float offsets)
    float* ws = (float*)d_ws;
    unsigned* featb  = (unsigned*)ws;                // N*64 uints = 3,200,000
    unsigned* hb     = (unsigned*)(ws + 3200000);    // N*64 uints (bf16 layer0 out)
    float*    hout   = ws + 6400000;                 // N*128 f32 (layer1 out)
    float*    el     = ws + 12800000;                // 200,000
    float*    er     = ws + 13000000;                // 200,000
    int*      row_st = (int*)(ws + 13200000);        // 50,001 (pad to 50,004)
    int*      deg    = (int*)(ws + 13250004);        // 50,000
    int*      rank   = (int*)(ws + 13300004);        // 800,000
    int*      csrsrc = (int*)(ws + 14100004);        // 800,000
    int*      partial= (int*)(ws + 14900004);        // 196 (pad to 200)
    unsigned* pkeys  = (unsigned*)(ws + 14900204);   // 8,192
    unsigned* wf0    = (unsigned*)(ws + 14908396);   // 8,192 uints (16B-aligned)
    unsigned* wf1    = (unsigned*)(ws + 14916588);   // 8,192 uints

    // prep (W-frags, deg/pkeys zero) then CSR counting
    prep_kernel<<<16 + SCAN_NB + 32, 256, 0, stream>>>(W0, W1, wf0, wf1, deg, pkeys);
    hist_kernel<<<EDGE_NB, 256, 0, stream>>>(edst, deg, rank);
    partial_kernel<<<SCAN_NB, 256, 0, stream>>>(deg, partial);
    csr_offsets_kernel<<<SCAN_NB, 256, 0, stream>>>(deg, partial, row_st);

    // CSR scatter (rank-based) fused with layer-0 feat (independent work)
    scatter_feat0_kernel<<<EDGE_NB + FEAT_NB, 256, 0, stream>>>(
        esrc, edst, rank, row_st, csrsrc, emb, word_ids, wf0, al0, ar0, featb, el, er);

    // layer 0 aggregate -> packed bf16 node features; layer 1
    gat_aggregate_t<1><<<12500, 256, 0, stream>>>(row_st, csrsrc, featb, el, er, nullptr, hb);
    feat_kernel_t<1><<<FEAT_NB, 256, 0, stream>>>(hb, nullptr, wf1, al1, ar1, featb, el, er);
    gat_aggregate_t<0><<<12500, 256, 0, stream>>>(row_st, csrsrc, featb, el, er, hout, nullptr);

    pool_kernel<<<POOL_NB, 256, 0, stream>>>(gid, hout, pkeys);
    logits_final_kernel<<<1, 256, 0, stream>>>(pkeys, out_w, out_b, y_data, out);
}